// Round 4
// baseline (161.480 us; speedup 1.0000x reference)
//
#include <hip/hip_runtime.h>
#include <hip/hip_bf16.h>
#include <stdint.h>

#define NN 8192
#define INF 128
#define OUTF 64
#define ALPHA 0.2f

typedef __attribute__((ext_vector_type(8))) short s16x8;
typedef __attribute__((ext_vector_type(4))) float f32x4;
typedef __attribute__((ext_vector_type(4))) int i32x4;

__device__ __forceinline__ unsigned short f2bf(float f) {
    union { float f; unsigned int u; } v; v.f = f;
    return (unsigned short)((v.u + 0x8000u) >> 16);   // round-half-up, 2 ops
}

// Kernel 1: Wh = h@W -> Wh1, Wh2 (f32), WhbT (bf16 [64][8192]), B1=e^Wh2, B2=e^{0.2 Wh2}
__global__ void prep_kernel(const float* __restrict__ h, const float* __restrict__ W,
                            const float* __restrict__ a,
                            float* __restrict__ Wh1, float* __restrict__ Wh2,
                            unsigned short* __restrict__ WhbT,
                            float* __restrict__ B1, float* __restrict__ B2) {
    __shared__ float ldsW[INF * OUTF];
    int t = threadIdx.x;
    for (int idx = t; idx < INF * OUTF; idx += 256) ldsW[idx] = W[idx];
    __syncthreads();
    int r = blockIdx.x * 4 + (t >> 6);
    int c = t & 63;
    const float4* h4 = reinterpret_cast<const float4*>(h + (size_t)r * INF);
    float dot = 0.f;
#pragma unroll
    for (int kk = 0; kk < INF / 4; ++kk) {
        float4 hv = h4[kk];
        dot += hv.x * ldsW[(4 * kk + 0) * OUTF + c];
        dot += hv.y * ldsW[(4 * kk + 1) * OUTF + c];
        dot += hv.z * ldsW[(4 * kk + 2) * OUTF + c];
        dot += hv.w * ldsW[(4 * kk + 3) * OUTF + c];
    }
    // proper RNE for WhbT (feeds MFMA B)
    union { float f; unsigned int u; } vv; vv.f = dot;
    unsigned int rr = vv.u + 0x7fffu + ((vv.u >> 16) & 1u);
    WhbT[(size_t)c * NN + r] = (unsigned short)(rr >> 16);
    float v1 = dot * a[c];
    float v2 = dot * a[OUTF + c];
#pragma unroll
    for (int off = 32; off >= 1; off >>= 1) {
        v1 += __shfl_xor(v1, off, 64);
        v2 += __shfl_xor(v2, off, 64);
    }
    if (c == 0) {
        Wh1[r] = v1; Wh2[r] = v2;
        B1[r] = __expf(v2);
        B2[r] = __expf(ALPHA * v2);
    }
}

__global__ void max_kernel(const float* __restrict__ Wh2, float* __restrict__ maxOut) {
    __shared__ float red[4];
    int t = threadIdx.x;
    float m = -3.4e38f;
    for (int i = t; i < NN; i += 256) m = fmaxf(m, Wh2[i]);
#pragma unroll
    for (int off = 32; off >= 1; off >>= 1) m = fmaxf(m, __shfl_xor(m, off, 64));
    if ((t & 63) == 0) red[t >> 6] = m;
    __syncthreads();
    if (t == 0) maxOut[0] = fmaxf(fmaxf(red[0], red[1]), fmaxf(red[2], red[3]));
}

// Kernel 2: barrier-free fused attention. Wave = 16 rows x 1024 j. No LDS.
// p_ij = adj * (x>0 ? A1_i*B1_j : A2_i*B2_j); branch via B1_j > e^{-Wh1_i}.
// Row-sum s via MFMA against a ones fragment. Per-q sliced stores (no atomics).
__launch_bounds__(256, 4)
__global__ void attn_kernel(const int* __restrict__ adj,
                            const float* __restrict__ Wh1,
                            const unsigned short* __restrict__ WhbT,
                            const float* __restrict__ maxW2,
                            const float* __restrict__ B1, const float* __restrict__ B2,
                            float* __restrict__ accS, float* __restrict__ sS) {
    const int tid = threadIdx.x;
    const int w = tid >> 6;
    const int l = tid & 63;
    const int il = l & 15;
    const int ks = l >> 4;
    const int bx = blockIdx.x;
    const int q = bx & 7;                      // j-group == XCD (round-robin)
    const int rt = (bx >> 3) * 4 + w;          // row tile 0..511
    const int rowbase = rt * 16;
    const int i = rowbase + il;
    const int jbase = q * (NN / 8);

    const float wh1 = Wh1[i];
    float M = wh1 + maxW2[0];
    M = fmaxf(M, ALPHA * M);
    const float A1 = __expf(wh1 - M);
    const float A2 = __expf(ALPHA * wh1 - M);
    const float T  = __expf(-wh1);             // B1_j > T  <=>  Wh1_i + Wh2_j > 0

    f32x4 acc[4] = {{0,0,0,0},{0,0,0,0},{0,0,0,0},{0,0,0,0}};
    f32x4 acc_s = {0,0,0,0};
    s16x8 ones;
#pragma unroll
    for (int b = 0; b < 8; ++b) ones[b] = (short)0x3F80;  // bf16 1.0

    const size_t adjRow = (size_t)i * NN;
    for (int it = 0; it < (NN / 8) / 32; ++it) {
        const int j0 = jbase + it * 32 + ks * 8;
        i32x4 a0 = __builtin_nontemporal_load(reinterpret_cast<const i32x4*>(adj + adjRow + j0));
        i32x4 a1 = __builtin_nontemporal_load(reinterpret_cast<const i32x4*>(adj + adjRow + j0 + 4));
        float4 b1a = *reinterpret_cast<const float4*>(B1 + j0);
        float4 b1b = *reinterpret_cast<const float4*>(B1 + j0 + 4);
        float4 b2a = *reinterpret_cast<const float4*>(B2 + j0);
        float4 b2b = *reinterpret_cast<const float4*>(B2 + j0 + 4);
        float b1v[8] = {b1a.x, b1a.y, b1a.z, b1a.w, b1b.x, b1b.y, b1b.z, b1b.w};
        float b2v[8] = {b2a.x, b2a.y, b2a.z, b2a.w, b2b.x, b2b.y, b2b.z, b2b.w};
        int   av[8]  = {a0.x, a0.y, a0.z, a0.w, a1.x, a1.y, a1.z, a1.w};
        s16x8 afrag;
#pragma unroll
        for (int b = 0; b < 8; ++b) {
            bool sel = b1v[b] > T;
            float Av = sel ? A1 : A2;
            float Bv = sel ? b1v[b] : b2v[b];
            float pf = Av * Bv;
            pf = av[b] ? pf : 0.f;
            afrag[b] = (short)f2bf(pf);
        }
        acc_s = __builtin_amdgcn_mfma_f32_16x16x32_bf16(afrag, ones, acc_s, 0, 0, 0);
#pragma unroll
        for (int ct = 0; ct < 4; ++ct) {
            s16x8 bfrag = *reinterpret_cast<const s16x8*>(WhbT + (size_t)(ct * 16 + il) * NN + j0);
            acc[ct] = __builtin_amdgcn_mfma_f32_16x16x32_bf16(afrag, bfrag, acc[ct], 0, 0, 0);
        }
    }

    // sliced stores: every (q,row,col) written exactly once -> no zeroing, no atomics
#pragma unroll
    for (int ct = 0; ct < 4; ++ct)
#pragma unroll
        for (int r = 0; r < 4; ++r)
            accS[((size_t)q * NN + rowbase + ks * 4 + r) * OUTF + ct * 16 + il] = acc[ct][r];
    if (il == 0) {
#pragma unroll
        for (int r = 0; r < 4; ++r)
            sS[q * NN + rowbase + ks * 4 + r] = acc_s[r];
    }
}

__global__ void finalize_kernel(const float* __restrict__ accS, const float* __restrict__ sS,
                                float* __restrict__ out) {
    int t4 = blockIdx.x * blockDim.x + threadIdx.x;   // float4 index within [NN*OUTF/4]
    if (t4 >= NN * OUTF / 4) return;
    int row = t4 >> 4;
    float ss = 0.f;
    float4 v = {0.f, 0.f, 0.f, 0.f};
#pragma unroll
    for (int qq = 0; qq < 8; ++qq) {
        ss += sS[qq * NN + row];
        float4 p = reinterpret_cast<const float4*>(accS)[(size_t)qq * (NN * OUTF / 4) + t4];
        v.x += p.x; v.y += p.y; v.z += p.z; v.w += p.w;
    }
    float inv = (ss > 0.f) ? 1.f / ss : 0.f;
    float r[4] = {v.x * inv, v.y * inv, v.z * inv, v.w * inv};
#pragma unroll
    for (int k = 0; k < 4; ++k) r[k] = (r[k] > 0.f) ? r[k] : (__expf(r[k]) - 1.f);
    reinterpret_cast<float4*>(out)[t4] = float4{r[0], r[1], r[2], r[3]};
}

extern "C" void kernel_launch(void* const* d_in, const int* in_sizes, int n_in,
                              void* d_out, int out_size, void* d_ws, size_t ws_size,
                              hipStream_t stream) {
    const float* h   = (const float*)d_in[0];
    const int*   adj = (const int*)d_in[1];
    const float* W   = (const float*)d_in[2];
    const float* a   = (const float*)d_in[3];
    float* out = (float*)d_out;

    char* ws = (char*)d_ws;
    float* Wh1 = (float*)(ws);                                   // 32 KB
    float* Wh2 = (float*)(ws + 32 * 1024);                       // 32 KB
    float* B1  = (float*)(ws + 64 * 1024);                       // 32 KB
    float* B2  = (float*)(ws + 96 * 1024);                       // 32 KB
    float* maxW2 = (float*)(ws + 128 * 1024);                    // 4 B
    unsigned short* WhbT = (unsigned short*)(ws + 160 * 1024);   // 1 MB
    float* accS = (float*)(ws + 2 * 1024 * 1024);                // 8 x 2 MB = 16 MB
    float* sS   = (float*)(ws + 18 * 1024 * 1024);               // 8 x 32 KB = 256 KB

    hipLaunchKernelGGL(prep_kernel, dim3(NN / 4), dim3(256), 0, stream,
                       h, W, a, Wh1, Wh2, WhbT, B1, B2);
    hipLaunchKernelGGL(max_kernel, dim3(1), dim3(256), 0, stream, Wh2, maxW2);
    hipLaunchKernelGGL(attn_kernel, dim3(1024), dim3(256), 0, stream,
                       adj, Wh1, WhbT, maxW2, B1, B2, accS, sS);
    hipLaunchKernelGGL(finalize_kernel, dim3(NN * OUTF / 4 / 256), dim3(256), 0, stream,
                       accS, sS, out);
}

// Round 5
// 93.797 us; speedup vs baseline: 1.7216x; 1.7216x over previous
//
#include <hip/hip_runtime.h>
#include <hip/hip_bf16.h>
#include <stdint.h>

#define NN 8192
#define INF 128
#define OUTF 64
#define ALPHA 0.2f
#define RB 128      // rows per attn block
#define JB 1024     // j-range per attn block
#define JPH 256     // j per staged phase

typedef __attribute__((ext_vector_type(8))) short s16x8;
typedef __attribute__((ext_vector_type(4))) float f32x4;
typedef __attribute__((ext_vector_type(4))) int i32x4;

typedef __attribute__((address_space(1))) const void ga_cv;
typedef __attribute__((address_space(3))) void lds_v;

__device__ __forceinline__ unsigned short f2bf(float f) {
    union { float f; unsigned int u; } v; v.f = f;
    return (unsigned short)((v.u + 0x8000u) >> 16);   // round-half-up (validated R4)
}

// Kernel 1: Wh = h@W -> Wh1, Wh2 (f32), WhbT (bf16 [64][8192]), B1=e^Wh2, B2=e^{0.2 Wh2}
__global__ void prep_kernel(const float* __restrict__ h, const float* __restrict__ W,
                            const float* __restrict__ a,
                            float* __restrict__ Wh1, float* __restrict__ Wh2,
                            unsigned short* __restrict__ WhbT,
                            float* __restrict__ B1, float* __restrict__ B2) {
    __shared__ float ldsW[INF * OUTF];
    int t = threadIdx.x;
    for (int idx = t; idx < INF * OUTF; idx += 256) ldsW[idx] = W[idx];
    __syncthreads();
    int r = blockIdx.x * 4 + (t >> 6);
    int c = t & 63;
    const float4* h4 = reinterpret_cast<const float4*>(h + (size_t)r * INF);
    float dot = 0.f;
#pragma unroll
    for (int kk = 0; kk < INF / 4; ++kk) {
        float4 hv = h4[kk];
        dot += hv.x * ldsW[(4 * kk + 0) * OUTF + c];
        dot += hv.y * ldsW[(4 * kk + 1) * OUTF + c];
        dot += hv.z * ldsW[(4 * kk + 2) * OUTF + c];
        dot += hv.w * ldsW[(4 * kk + 3) * OUTF + c];
    }
    union { float f; unsigned int u; } vv; vv.f = dot;
    unsigned int rr = vv.u + 0x7fffu + ((vv.u >> 16) & 1u);
    WhbT[(size_t)c * NN + r] = (unsigned short)(rr >> 16);   // RNE
    float v1 = dot * a[c];
    float v2 = dot * a[OUTF + c];
#pragma unroll
    for (int off = 32; off >= 1; off >>= 1) {
        v1 += __shfl_xor(v1, off, 64);
        v2 += __shfl_xor(v2, off, 64);
    }
    if (c == 0) {
        Wh1[r] = v1; Wh2[r] = v2;
        B1[r] = __expf(v2);
        B2[r] = __expf(ALPHA * v2);
    }
}

__global__ void max_kernel(const float* __restrict__ Wh2, float* __restrict__ maxOut) {
    __shared__ float red[4];
    int t = threadIdx.x;
    float m = -3.4e38f;
    for (int i = t; i < NN; i += 256) m = fmaxf(m, Wh2[i]);
#pragma unroll
    for (int off = 32; off >= 1; off >>= 1) m = fmaxf(m, __shfl_xor(m, off, 64));
    if ((t & 63) == 0) red[t >> 6] = m;
    __syncthreads();
    if (t == 0) maxOut[0] = fmaxf(fmaxf(red[0], red[1]), fmaxf(red[2], red[3]));
}

// Kernel 2: R3 structure (LDS-dbuf B-panel, barrier pipeline) + R4 exp-free
// scoring. p_ij = adj * (x>0 ? A1_i*B1_j : A2_i*B2_j), predicate B1_j > e^{-Wh1_i}.
// Row-sum via ones-MFMA. Per-q sliced stores (no atomics, no zero pass).
__launch_bounds__(512, 4)
__global__ void attn_kernel(const int* __restrict__ adj,
                            const float* __restrict__ Wh1,
                            const unsigned short* __restrict__ WhbT,
                            const float* __restrict__ maxW2,
                            const float* __restrict__ B1, const float* __restrict__ B2,
                            float* __restrict__ accS, float* __restrict__ sS) {
    __shared__ unsigned short Bpanel[2][64 * JPH];   // 2 x 32KB
    const int tid = threadIdx.x;
    const int w = tid >> 6;
    const int l = tid & 63;
    const int il = l & 15;
    const int ks = l >> 4;
    const int g = blockIdx.x >> 3;
    const int q = blockIdx.x & 7;      // j-group == XCD (round-robin)
    const int rowbase = g * RB + w * 16;
    const int i = rowbase + il;
    const int jbase = q * JB;

    const float wh1 = Wh1[i];
    float M = wh1 + maxW2[0];
    M = fmaxf(M, ALPHA * M);
    const float A1 = __expf(wh1 - M);
    const float A2 = __expf(ALPHA * wh1 - M);
    const float T  = __expf(-wh1);     // B1_j > T  <=>  Wh1_i + Wh2_j > 0

    const int c_lo = w * 8 + (l >> 5);
    const int jst = (l & 31) * 8;

#define STAGE(ph) { \
    unsigned short* dst = &Bpanel[(ph) & 1][w * 2048]; \
    _Pragma("unroll") \
    for (int k = 0; k < 4; ++k) { \
        int c = c_lo + 2 * k; \
        int jl = jst ^ ((c & 7) * 8); \
        const unsigned short* src = WhbT + (size_t)c * NN + jbase + (ph) * JPH + jl; \
        __builtin_amdgcn_global_load_lds((ga_cv*)src, (lds_v*)(dst + k * 512), 16, 0, 0); \
    } }

    f32x4 acc[4] = {{0,0,0,0},{0,0,0,0},{0,0,0,0},{0,0,0,0}};
    f32x4 acc_s = {0,0,0,0};
    s16x8 ones;
#pragma unroll
    for (int b = 0; b < 8; ++b) ones[b] = (short)0x3F80;  // bf16 1.0

    const size_t adjRow = (size_t)i * NN;
    const int swzmask = (il & 7) * 8;

    STAGE(0);
    for (int ph = 0; ph < JB / JPH; ++ph) {
        __syncthreads();
        if (ph < JB / JPH - 1) STAGE(ph + 1);
        const unsigned short* bp = &Bpanel[ph & 1][il * JPH];
#pragma unroll
        for (int ks8 = 0; ks8 < JPH / 32; ++ks8) {
            const int j0 = jbase + ph * JPH + ks8 * 32 + ks * 8;
            i32x4 a0 = *reinterpret_cast<const i32x4*>(adj + adjRow + j0);
            i32x4 a1 = *reinterpret_cast<const i32x4*>(adj + adjRow + j0 + 4);
            float4 b1a = *reinterpret_cast<const float4*>(B1 + j0);
            float4 b1b = *reinterpret_cast<const float4*>(B1 + j0 + 4);
            float4 b2a = *reinterpret_cast<const float4*>(B2 + j0);
            float4 b2b = *reinterpret_cast<const float4*>(B2 + j0 + 4);
            float b1v[8] = {b1a.x, b1a.y, b1a.z, b1a.w, b1b.x, b1b.y, b1b.z, b1b.w};
            float b2v[8] = {b2a.x, b2a.y, b2a.z, b2a.w, b2b.x, b2b.y, b2b.z, b2b.w};
            int   av[8]  = {a0.x, a0.y, a0.z, a0.w, a1.x, a1.y, a1.z, a1.w};
            s16x8 afrag;
#pragma unroll
            for (int b = 0; b < 8; ++b) {
                bool sel = b1v[b] > T;
                float Av = sel ? A1 : A2;
                float Bv = sel ? b1v[b] : b2v[b];
                float pf = Av * Bv;
                pf = av[b] ? pf : 0.f;
                afrag[b] = (short)f2bf(pf);
            }
            acc_s = __builtin_amdgcn_mfma_f32_16x16x32_bf16(afrag, ones, acc_s, 0, 0, 0);
            const int off_e = (ks8 * 32 + ks * 8) ^ swzmask;
#pragma unroll
            for (int ct = 0; ct < 4; ++ct) {
                s16x8 bfrag = *reinterpret_cast<const s16x8*>(bp + ct * 16 * JPH + off_e);
                acc[ct] = __builtin_amdgcn_mfma_f32_16x16x32_bf16(afrag, bfrag, acc[ct], 0, 0, 0);
            }
        }
    }

    // sliced stores: every (q,row,col) written exactly once
#pragma unroll
    for (int ct = 0; ct < 4; ++ct)
#pragma unroll
        for (int r = 0; r < 4; ++r)
            accS[((size_t)q * NN + rowbase + ks * 4 + r) * OUTF + ct * 16 + il] = acc[ct][r];
    if (il == 0) {
#pragma unroll
        for (int r = 0; r < 4; ++r)
            sS[q * NN + rowbase + ks * 4 + r] = acc_s[r];
    }
}

__global__ void finalize_kernel(const float* __restrict__ accS, const float* __restrict__ sS,
                                float* __restrict__ out) {
    int t4 = blockIdx.x * blockDim.x + threadIdx.x;
    if (t4 >= NN * OUTF / 4) return;
    int row = t4 >> 4;
    float ss = 0.f;
    float4 v = {0.f, 0.f, 0.f, 0.f};
#pragma unroll
    for (int qq = 0; qq < 8; ++qq) {
        ss += sS[qq * NN + row];
        float4 p = reinterpret_cast<const float4*>(accS)[(size_t)qq * (NN * OUTF / 4) + t4];
        v.x += p.x; v.y += p.y; v.z += p.z; v.w += p.w;
    }
    float inv = (ss > 0.f) ? 1.f / ss : 0.f;
    float r[4] = {v.x * inv, v.y * inv, v.z * inv, v.w * inv};
#pragma unroll
    for (int k = 0; k < 4; ++k) r[k] = (r[k] > 0.f) ? r[k] : (__expf(r[k]) - 1.f);
    reinterpret_cast<float4*>(out)[t4] = float4{r[0], r[1], r[2], r[3]};
}

extern "C" void kernel_launch(void* const* d_in, const int* in_sizes, int n_in,
                              void* d_out, int out_size, void* d_ws, size_t ws_size,
                              hipStream_t stream) {
    const float* h   = (const float*)d_in[0];
    const int*   adj = (const int*)d_in[1];
    const float* W   = (const float*)d_in[2];
    const float* a   = (const float*)d_in[3];
    float* out = (float*)d_out;

    char* ws = (char*)d_ws;
    float* Wh1 = (float*)(ws);                                   // 32 KB
    float* Wh2 = (float*)(ws + 32 * 1024);                       // 32 KB
    float* B1  = (float*)(ws + 64 * 1024);                       // 32 KB
    float* B2  = (float*)(ws + 96 * 1024);                       // 32 KB
    float* maxW2 = (float*)(ws + 128 * 1024);                    // 4 B
    unsigned short* WhbT = (unsigned short*)(ws + 160 * 1024);   // 1 MB
    float* accS = (float*)(ws + 2 * 1024 * 1024);                // 8 x 2 MB = 16 MB
    float* sS   = (float*)(ws + 18 * 1024 * 1024);               // 8 x 32 KB

    hipLaunchKernelGGL(prep_kernel, dim3(NN / 4), dim3(256), 0, stream,
                       h, W, a, Wh1, Wh2, WhbT, B1, B2);
    hipLaunchKernelGGL(max_kernel, dim3(1), dim3(256), 0, stream, Wh2, maxW2);
    hipLaunchKernelGGL(attn_kernel, dim3((NN / RB) * (NN / JB)), dim3(512), 0, stream,
                       adj, Wh1, WhbT, maxW2, B1, B2, accS, sS);
    hipLaunchKernelGGL(finalize_kernel, dim3(NN * OUTF / 4 / 256), dim3(256), 0, stream,
                       accS, sS, out);
}